// Round 8
// baseline (144.502 us; speedup 1.0000x reference)
//
#include <hip/hip_runtime.h>

// Attention: B=8, N=4096, D=64, fp32 in/out, causal + padding mask.
// R8: R7 core (32x32x16 MFMA, S^T, fixed-ref log2 softmax, shfl-based P
//     transpose, async global_load_lds from prep'd bf16 ws) but 8 waves/
//     block processing TWO k-tiles per barrier interval (waves 0-3 tile
//     2ss, waves 4-7 tile 2ss+1). Chain halves (32 supersteps), waves/SIMD
//     doubles (4). Epilogue: 4-way add-merge via aliased LDS, direct f4
//     stores (no transpose round-trip).

#define BATCH 8
#define SEQ   4096
#define DIM   64
#define NKT   (SEQ / 64)

typedef __attribute__((ext_vector_type(8)))  short bf16x8;
typedef __attribute__((ext_vector_type(16))) float f32x16;

__device__ inline short f2bf(float f) {
    unsigned u = __builtin_bit_cast(unsigned, f);
    u += 0x7FFFu + ((u >> 16) & 1u);   // RNE
    return (short)(u >> 16);
}
__device__ inline unsigned pk2bf(float a, float b) {
    unsigned ua = __builtin_bit_cast(unsigned, a) + 0x8000u;
    unsigned ub = __builtin_bit_cast(unsigned, b) + 0x8000u;
    return __builtin_amdgcn_perm(ub, ua, 0x07060302u);
}
__device__ inline float fast_exp2(float x) {
#if __has_builtin(__builtin_amdgcn_exp2f)
    return __builtin_amdgcn_exp2f(x);
#else
    return exp2f(x);
#endif
}
__device__ inline bf16x8 pack8(const float4& a, const float4& b) {
    bf16x8 r;
    r[0] = f2bf(a.x); r[1] = f2bf(a.y); r[2] = f2bf(a.z); r[3] = f2bf(a.w);
    r[4] = f2bf(b.x); r[5] = f2bf(b.y); r[6] = f2bf(b.z); r[7] = f2bf(b.w);
    return r;
}
__device__ inline void gl_lds16(const void* g, void* l) {
    __builtin_amdgcn_global_load_lds(
        (const __attribute__((address_space(1))) void*)g,
        (__attribute__((address_space(3))) void*)l, 16, 0, 0);
}

// ---- pre-pass: fp32 K,V -> bf16 tiles, MFMA-fragment order ----
// K tile: cell(dchunk 0..7, key 0..63) = dchunk*64+key, 8 shorts (d in chunk)
// V tile: cell(kchunk 0..7, d 0..63)  = kchunk*64+d,   8 shorts (key in chunk)
__global__ __launch_bounds__(256)
void prep_kv(const float* __restrict__ kg, const float* __restrict__ vg,
             short* __restrict__ kw, short* __restrict__ vw) {
    const int tile = blockIdx.x;            // b*NKT + kt
    const float* kp = kg + (size_t)tile * 64 * DIM;
    const float* vp = vg + (size_t)tile * 64 * DIM;
    short* ko = kw + (size_t)tile * 4096;
    short* vo = vw + (size_t)tile * 4096;
    const int t = threadIdx.x;
#pragma unroll
    for (int i = 0; i < 4; ++i) {
        const int flat = i * 256 + t;
        const int key = flat >> 4, d0 = (flat & 15) * 4;
        const float4 kv = *(const float4*)(kp + (size_t)key * DIM + d0);
        uint2 kpk;
        kpk.x = pk2bf(kv.x, kv.y); kpk.y = pk2bf(kv.z, kv.w);
        *(uint2*)(ko + (((d0 >> 3) << 6) + key) * 8 + (d0 & 7)) = kpk;
        const float4 vv = *(const float4*)(vp + (size_t)key * DIM + d0);
        const int kc = key >> 3, jk = key & 7;
        vo[((kc << 6) + d0 + 0) * 8 + jk] = f2bf(vv.x);
        vo[((kc << 6) + d0 + 1) * 8 + jk] = f2bf(vv.y);
        vo[((kc << 6) + d0 + 2) * 8 + jk] = f2bf(vv.z);
        vo[((kc << 6) + d0 + 3) * 8 + jk] = f2bf(vv.w);
    }
}

template <bool WS>
__global__ __launch_bounds__(512, 4)
void attn_fwd(const float* __restrict__ qg, const float* __restrict__ kg,
              const float* __restrict__ vg, const int* __restrict__ mg,
              float* __restrict__ og, const short* __restrict__ kw,
              const short* __restrict__ vw) {
    // Kb[2][8192]sh (32KB) | Vb[2][8192]sh (32KB) | Lb[8][32]f (1KB)
    __shared__ __align__(16) char smem[66560];
    short* KbS = (short*)smem;              // pair-buffered, tile tp at +tp*4096
    short* VbS = (short*)(smem + 32768);
    float* Lb  = (float*)(smem + 65536);
    float* ObF = (float*)smem;              // epilogue alias: 6 regions x 8192 B

    const int t    = threadIdx.x;
    const int w    = t >> 6;        // wave 0..7
    const int L    = t & 63;
    const int q31  = L & 31;
    const int h    = L >> 5;
    const int qsub = w & 1;         // q sub-tile (32 rows)
    const int kh   = (w >> 1) & 1;  // key half within tile
    const int tp   = w >> 2;        // tile parity within superstep

    // b = id&7 (batch <-> XCD L2 affinity); adjacent j's pair long+short chains
    const int id = blockIdx.x;
    const int b  = id & 7;
    const int j  = id >> 3;
    const int qb = (j & 1) ? (j >> 1) : (63 - (j >> 1));
    const int qbase  = qb * 64;
    const int ntiles = qb + 1;
    const int nss    = (ntiles + 1) >> 1;

    const float* qp = qg + (size_t)b * SEQ * DIM;
    const float* kp = kg + (size_t)b * SEQ * DIM;
    const float* vp = vg + (size_t)b * SEQ * DIM;
    const int*   mp = mg + (size_t)b * SEQ;
    const short* kwb = WS ? kw + (size_t)b * NKT * 4096 : nullptr;
    const short* vwb = WS ? vw + (size_t)b * NKT * 4096 : nullptr;

    const int qrow = qbase + qsub * 32 + q31;   // lane's q column (S^T)
    const float qscale = 0.125f * 1.44269504088896340736f; // 1/sqrt(64)*log2e

    // Q B-fragments (32x32x16): B[k=16c+8h+jj][n=q31], scale folded
    bf16x8 Qf[4];
#pragma unroll
    for (int c = 0; c < 4; ++c) {
        const float* src = qp + (size_t)qrow * DIM + c * 16 + h * 8;
        float4 x = *(const float4*)src;
        float4 y = *(const float4*)(src + 4);
        x.x *= qscale; x.y *= qscale; x.z *= qscale; x.w *= qscale;
        y.x *= qscale; y.y *= qscale; y.z *= qscale; y.w *= qscale;
        Qf[c] = pack8(x, y);
    }

    // async stage of tile-pair pp into buffer bs (pairs are 16KB contiguous)
    auto stage = [&](int bs, int pp) {
        const short* ks = kwb + (size_t)pp * 8192;
        const short* vs = vwb + (size_t)pp * 8192;
#pragma unroll
        for (int it = 0; it < 2; ++it) {
            const int off = (w << 10) + (it << 9);   // wave-uniform base
            gl_lds16(ks + off + (L << 3), KbS + bs * 8192 + off);
            gl_lds16(vs + off + (L << 3), VbS + bs * 8192 + off);
        }
    };

    float lsum = 0.0f;
    f32x16 Oacc[2];
#pragma unroll
    for (int nb = 0; nb < 2; ++nb)
#pragma unroll
        for (int r = 0; r < 16; ++r) Oacc[nb][r] = 0.0f;

    if constexpr (WS) stage(0, 0);

    for (int ss = 0; ss < nss; ++ss) {
        const int cur = WS ? (ss & 1) : 0;

        if constexpr (WS) {
            __syncthreads();   // pair ss landed (vmcnt drained); prev reads done
            if (ss + 1 < nss) stage(cur ^ 1, ss + 1);
        } else {
            __syncthreads();
#pragma unroll
            for (int i = 0; i < 4; ++i) {
                const int flat = i * 512 + t;          // 0..2047
                const int tl = flat >> 10;             // tile in pair
                const int rem = flat & 1023;
                const int key = rem >> 4, d0 = (rem & 15) * 4;
                const size_t row = (size_t)((2 * ss + tl) * 64 + key);
                const float4 kv = *(const float4*)(kp + row * DIM + d0);
                uint2 kk;
                kk.x = pk2bf(kv.x, kv.y); kk.y = pk2bf(kv.z, kv.w);
                *(uint2*)&KbS[tl * 4096 + (((d0 >> 3) << 6) + key) * 8 + (d0 & 7)] = kk;
                const float4 vv = *(const float4*)(vp + row * DIM + d0);
                const int kc = key >> 3, jk = key & 7;
                VbS[tl * 4096 + ((kc << 6) + d0 + 0) * 8 + jk] = f2bf(vv.x);
                VbS[tl * 4096 + ((kc << 6) + d0 + 1) * 8 + jk] = f2bf(vv.y);
                VbS[tl * 4096 + ((kc << 6) + d0 + 2) * 8 + jk] = f2bf(vv.z);
                VbS[tl * 4096 + ((kc << 6) + d0 + 3) * 8 + jk] = f2bf(vv.w);
            }
            __syncthreads();
        }

        const int tile = 2 * ss + tp;
        if (tile < ntiles) {                 // wave-uniform
            const short* Kt = KbS + cur * 8192 + tp * 4096;
            const short* Vt = VbS + cur * 8192 + tp * 4096;

            // mask int4 loads (L1-hot, overlapped with MFMAs)
            int4 Md[4];
#pragma unroll
            for (int g = 0; g < 4; ++g)
                Md[g] = *(const int4*)&mp[tile * 64 + kh * 32 + 8 * g + 4 * h];

            // ---- S^T = K @ Q^T : D[m=key_local][n=q], 4 MFMAs over d
            f32x16 sa;
#pragma unroll
            for (int r = 0; r < 16; ++r) sa[r] = 0.0f;
#pragma unroll
            for (int c = 0; c < 4; ++c) {
                bf16x8 kf = *(const bf16x8*)&Kt[(((2 * c + h) << 6) + kh * 32 + q31) * 8];
                sa = __builtin_amdgcn_mfma_f32_32x32x16_bf16(kf, Qf[c], sa, 0, 0, 0);
            }

            // ---- mask + exp2 (fixed-ref softmax). key row = 4h + 8g + e
            const bool diag = (tile == ntiles - 1);
            float p[16];
#pragma unroll
            for (int g = 0; g < 4; ++g) {
                const int mi[4] = {Md[g].x, Md[g].y, Md[g].z, Md[g].w};
#pragma unroll
                for (int e = 0; e < 4; ++e) {
                    const int reg = g * 4 + e;
                    float s = sa[reg];
                    bool keep = (mi[e] != 0);
                    if (diag) {
                        const int keyg = tile * 64 + kh * 32 + 4 * h + 8 * g + e;
                        keep = keep && (keyg <= qrow);
                    }
                    s = keep ? s : -1e30f;
                    p[reg] = fast_exp2(fminf(s, 80.0f));
                    lsum += p[reg];
                }
            }

            // ---- P -> B-fragment via lane^32 exchange
            unsigned u[8], su[8];
#pragma unroll
            for (int i = 0; i < 8; ++i) u[i] = pk2bf(p[2 * i], p[2 * i + 1]);
#pragma unroll
            for (int i = 0; i < 8; ++i) su[i] = (unsigned)__shfl_xor((int)u[i], 32);
            int4 fi0 = h ? (int4){(int)su[2], (int)su[3], (int)u[2], (int)u[3]}
                         : (int4){(int)u[0], (int)u[1], (int)su[0], (int)su[1]};
            int4 fi1 = h ? (int4){(int)su[6], (int)su[7], (int)u[6], (int)u[7]}
                         : (int4){(int)u[4], (int)u[5], (int)su[4], (int)su[5]};
            bf16x8 pf0 = __builtin_bit_cast(bf16x8, fi0);
            bf16x8 pf1 = __builtin_bit_cast(bf16x8, fi1);

            // ---- O^T += V^T @ P^T : D[m=d_local][n=q]
#pragma unroll
            for (int kk = 0; kk < 2; ++kk) {
                const bf16x8 pf = kk ? pf1 : pf0;
#pragma unroll
                for (int nb = 0; nb < 2; ++nb) {
                    bf16x8 vf = *(const bf16x8*)&Vt[(((4 * kh + 2 * kk + h) << 6) + nb * 32 + q31) * 8];
                    Oacc[nb] = __builtin_amdgcn_mfma_f32_32x32x16_bf16(vf, pf, Oacc[nb], 0, 0, 0);
                }
            }
        }
    }

    // ---- epilogue: 4-way merge (kh x tp) per qsub, normalize, store
    lsum += __shfl_xor(lsum, 32);      // both h halves -> per-q l for this wave

    __syncthreads();                    // all K/V LDS reads done -> alias safe
    if (w >= 2) {
        // region r: qsub 0 <- waves {2,4,6} -> r 0,1,2 ; qsub 1 <- {3,5,7} -> 3,4,5
        const int r = ((w - 2) >> 1) + qsub * 3;
        float* Ow = ObF + r * 2048;     // [d 0..63][q 0..31]
#pragma unroll
        for (int nb = 0; nb < 2; ++nb)
#pragma unroll
            for (int g = 0; g < 4; ++g)
#pragma unroll
                for (int e = 0; e < 4; ++e)
                    Ow[(nb * 32 + 4 * h + 8 * g + e) * 32 + q31] = Oacc[nb][g * 4 + e];
        if (h == 0) Lb[w * 32 + q31] = lsum;
    }
    __syncthreads();
    if (w < 2) {
        const int s = w;   // qsub
        const float ltot = lsum + Lb[(s + 2) * 32 + q31] + Lb[(s + 4) * 32 + q31]
                                + Lb[(s + 6) * 32 + q31];
        const float inv = 1.0f / ltot;
        const float* R0 = ObF + (s * 3 + 0) * 2048;
        const float* R1 = ObF + (s * 3 + 1) * 2048;
        const float* R2 = ObF + (s * 3 + 2) * 2048;
        float* op = og + (size_t)b * SEQ * DIM + (size_t)(qbase + s * 32 + q31) * DIM;
#pragma unroll
        for (int nb = 0; nb < 2; ++nb)
#pragma unroll
            for (int g = 0; g < 4; ++g) {
                float4 v4;
                float* vv = (float*)&v4;
#pragma unroll
                for (int e = 0; e < 4; ++e) {
                    const int d = nb * 32 + 4 * h + 8 * g + e;
                    vv[e] = (Oacc[nb][g * 4 + e] + R0[d * 32 + q31] + R1[d * 32 + q31]
                             + R2[d * 32 + q31]) * inv;
                }
                *(float4*)&op[nb * 32 + 4 * h + 8 * g] = v4;
            }
    }
}

extern "C" void kernel_launch(void* const* d_in, const int* in_sizes, int n_in,
                              void* d_out, int out_size, void* d_ws, size_t ws_size,
                              hipStream_t stream) {
    (void)in_sizes; (void)n_in; (void)out_size;
    const float* q = (const float*)d_in[0];
    const float* k = (const float*)d_in[1];
    const float* v = (const float*)d_in[2];
    const int*   m = (const int*)d_in[3];
    float* o = (float*)d_out;
    const size_t need = (size_t)BATCH * NKT * 4096 * sizeof(short) * 2; // 8 MB
    if (ws_size >= need) {
        short* kw = (short*)d_ws;
        short* vw = kw + (size_t)BATCH * NKT * 4096;
        prep_kv<<<dim3(BATCH * NKT), 256, 0, stream>>>(k, v, kw, vw);
        attn_fwd<true><<<dim3(512), 512, 0, stream>>>(q, k, v, m, o, kw, vw);
    } else {
        attn_fwd<false><<<dim3(512), 512, 0, stream>>>(q, k, v, m, o, nullptr, nullptr);
    }
}

// Round 9
// 141.123 us; speedup vs baseline: 1.0239x; 1.0239x over previous
//
#include <hip/hip_runtime.h>

// Attention: B=8, N=4096, D=64, fp32 in/out, causal + padding mask.
// R9: R8 core (32x32x16 MFMA, S^T, fixed-ref log2 softmax, shfl-based P
//     transpose, async global_load_lds pair staging, 8 waves / 2 tiles per
//     barrier) with the R5 balanced grid mapping restored:
//     qb = (j<32) ? 63-j : j-32  ->  co-resident blocks (id, id+256) have
//     complementary chain lengths summing to 65 tiles (R7/R8's interleaved
//     mapping gave sums 16..112 -> 112-tile serial tail = the 70us plateau).

#define BATCH 8
#define SEQ   4096
#define DIM   64
#define NKT   (SEQ / 64)

typedef __attribute__((ext_vector_type(8)))  short bf16x8;
typedef __attribute__((ext_vector_type(16))) float f32x16;

__device__ inline short f2bf(float f) {
    unsigned u = __builtin_bit_cast(unsigned, f);
    u += 0x7FFFu + ((u >> 16) & 1u);   // RNE
    return (short)(u >> 16);
}
__device__ inline unsigned pk2bf(float a, float b) {
    unsigned ua = __builtin_bit_cast(unsigned, a) + 0x8000u;
    unsigned ub = __builtin_bit_cast(unsigned, b) + 0x8000u;
    return __builtin_amdgcn_perm(ub, ua, 0x07060302u);
}
__device__ inline float fast_exp2(float x) {
#if __has_builtin(__builtin_amdgcn_exp2f)
    return __builtin_amdgcn_exp2f(x);
#else
    return exp2f(x);
#endif
}
__device__ inline bf16x8 pack8(const float4& a, const float4& b) {
    bf16x8 r;
    r[0] = f2bf(a.x); r[1] = f2bf(a.y); r[2] = f2bf(a.z); r[3] = f2bf(a.w);
    r[4] = f2bf(b.x); r[5] = f2bf(b.y); r[6] = f2bf(b.z); r[7] = f2bf(b.w);
    return r;
}
__device__ inline void gl_lds16(const void* g, void* l) {
    __builtin_amdgcn_global_load_lds(
        (const __attribute__((address_space(1))) void*)g,
        (__attribute__((address_space(3))) void*)l, 16, 0, 0);
}

// ---- pre-pass: fp32 K,V -> bf16 tiles, MFMA-fragment order ----
// K tile: cell(dchunk 0..7, key 0..63) = dchunk*64+key, 8 shorts (d in chunk)
// V tile: cell(kchunk 0..7, d 0..63)  = kchunk*64+d,   8 shorts (key in chunk)
__global__ __launch_bounds__(256)
void prep_kv(const float* __restrict__ kg, const float* __restrict__ vg,
             short* __restrict__ kw, short* __restrict__ vw) {
    const int tile = blockIdx.x;            // b*NKT + kt
    const float* kp = kg + (size_t)tile * 64 * DIM;
    const float* vp = vg + (size_t)tile * 64 * DIM;
    short* ko = kw + (size_t)tile * 4096;
    short* vo = vw + (size_t)tile * 4096;
    const int t = threadIdx.x;
#pragma unroll
    for (int i = 0; i < 4; ++i) {
        const int flat = i * 256 + t;
        const int key = flat >> 4, d0 = (flat & 15) * 4;
        const float4 kv = *(const float4*)(kp + (size_t)key * DIM + d0);
        uint2 kpk;
        kpk.x = pk2bf(kv.x, kv.y); kpk.y = pk2bf(kv.z, kv.w);
        *(uint2*)(ko + (((d0 >> 3) << 6) + key) * 8 + (d0 & 7)) = kpk;
        const float4 vv = *(const float4*)(vp + (size_t)key * DIM + d0);
        const int kc = key >> 3, jk = key & 7;
        vo[((kc << 6) + d0 + 0) * 8 + jk] = f2bf(vv.x);
        vo[((kc << 6) + d0 + 1) * 8 + jk] = f2bf(vv.y);
        vo[((kc << 6) + d0 + 2) * 8 + jk] = f2bf(vv.z);
        vo[((kc << 6) + d0 + 3) * 8 + jk] = f2bf(vv.w);
    }
}

template <bool WS>
__global__ __launch_bounds__(512, 4)
void attn_fwd(const float* __restrict__ qg, const float* __restrict__ kg,
              const float* __restrict__ vg, const int* __restrict__ mg,
              float* __restrict__ og, const short* __restrict__ kw,
              const short* __restrict__ vw) {
    // Kb[2][8192]sh (32KB) | Vb[2][8192]sh (32KB) | Lb[8][32]f (1KB)
    __shared__ __align__(16) char smem[66560];
    short* KbS = (short*)smem;              // pair-buffered, tile tp at +tp*4096
    short* VbS = (short*)(smem + 32768);
    float* Lb  = (float*)(smem + 65536);
    float* ObF = (float*)smem;              // epilogue alias: 6 regions x 8192 B

    const int t    = threadIdx.x;
    const int w    = t >> 6;        // wave 0..7
    const int L    = t & 63;
    const int q31  = L & 31;
    const int h    = L >> 5;
    const int qsub = w & 1;         // q sub-tile (32 rows)
    const int kh   = (w >> 1) & 1;  // key half within tile
    const int tp   = w >> 2;        // tile parity within superstep

    // b = id&7 (batch <-> XCD L2 affinity); ids i and i+256 -> qb summing 64
    const int id = blockIdx.x;
    const int b  = id & 7;
    const int j  = id >> 3;
    const int qb = (j < 32) ? (63 - j) : (j - 32);
    const int qbase  = qb * 64;
    const int ntiles = qb + 1;
    const int nss    = (ntiles + 1) >> 1;

    const float* qp = qg + (size_t)b * SEQ * DIM;
    const float* kp = kg + (size_t)b * SEQ * DIM;
    const float* vp = vg + (size_t)b * SEQ * DIM;
    const int*   mp = mg + (size_t)b * SEQ;
    const short* kwb = WS ? kw + (size_t)b * NKT * 4096 : nullptr;
    const short* vwb = WS ? vw + (size_t)b * NKT * 4096 : nullptr;

    const int qrow = qbase + qsub * 32 + q31;   // lane's q column (S^T)
    const float qscale = 0.125f * 1.44269504088896340736f; // 1/sqrt(64)*log2e

    // Q B-fragments (32x32x16): B[k=16c+8h+jj][n=q31], scale folded
    bf16x8 Qf[4];
#pragma unroll
    for (int c = 0; c < 4; ++c) {
        const float* src = qp + (size_t)qrow * DIM + c * 16 + h * 8;
        float4 x = *(const float4*)src;
        float4 y = *(const float4*)(src + 4);
        x.x *= qscale; x.y *= qscale; x.z *= qscale; x.w *= qscale;
        y.x *= qscale; y.y *= qscale; y.z *= qscale; y.w *= qscale;
        Qf[c] = pack8(x, y);
    }

    // async stage of tile-pair pp into buffer bs (pairs are 16KB contiguous)
    auto stage = [&](int bs, int pp) {
        const short* ks = kwb + (size_t)pp * 8192;
        const short* vs = vwb + (size_t)pp * 8192;
#pragma unroll
        for (int it = 0; it < 2; ++it) {
            const int off = (w << 10) + (it << 9);   // wave-uniform base
            gl_lds16(ks + off + (L << 3), KbS + bs * 8192 + off);
            gl_lds16(vs + off + (L << 3), VbS + bs * 8192 + off);
        }
    };

    float lsum = 0.0f;
    f32x16 Oacc[2];
#pragma unroll
    for (int nb = 0; nb < 2; ++nb)
#pragma unroll
        for (int r = 0; r < 16; ++r) Oacc[nb][r] = 0.0f;

    if constexpr (WS) stage(0, 0);

    for (int ss = 0; ss < nss; ++ss) {
        const int cur = WS ? (ss & 1) : 0;

        if constexpr (WS) {
            __syncthreads();   // pair ss landed (vmcnt drained); prev reads done
            if (ss + 1 < nss) stage(cur ^ 1, ss + 1);
        } else {
            __syncthreads();
#pragma unroll
            for (int i = 0; i < 4; ++i) {
                const int flat = i * 512 + t;          // 0..2047
                const int tl = flat >> 10;             // tile in pair
                const int rem = flat & 1023;
                const int key = rem >> 4, d0 = (rem & 15) * 4;
                const size_t row = (size_t)((2 * ss + tl) * 64 + key);
                const float4 kv = *(const float4*)(kp + row * DIM + d0);
                uint2 kk;
                kk.x = pk2bf(kv.x, kv.y); kk.y = pk2bf(kv.z, kv.w);
                *(uint2*)&KbS[tl * 4096 + (((d0 >> 3) << 6) + key) * 8 + (d0 & 7)] = kk;
                const float4 vv = *(const float4*)(vp + row * DIM + d0);
                const int kc = key >> 3, jk = key & 7;
                VbS[tl * 4096 + ((kc << 6) + d0 + 0) * 8 + jk] = f2bf(vv.x);
                VbS[tl * 4096 + ((kc << 6) + d0 + 1) * 8 + jk] = f2bf(vv.y);
                VbS[tl * 4096 + ((kc << 6) + d0 + 2) * 8 + jk] = f2bf(vv.z);
                VbS[tl * 4096 + ((kc << 6) + d0 + 3) * 8 + jk] = f2bf(vv.w);
            }
            __syncthreads();
        }

        const int tile = 2 * ss + tp;
        if (tile < ntiles) {                 // wave-uniform
            const short* Kt = KbS + cur * 8192 + tp * 4096;
            const short* Vt = VbS + cur * 8192 + tp * 4096;

            // mask int4 loads (L1-hot, overlapped with MFMAs)
            int4 Md[4];
#pragma unroll
            for (int g = 0; g < 4; ++g)
                Md[g] = *(const int4*)&mp[tile * 64 + kh * 32 + 8 * g + 4 * h];

            // ---- S^T = K @ Q^T : D[m=key_local][n=q], 4 MFMAs over d
            f32x16 sa;
#pragma unroll
            for (int r = 0; r < 16; ++r) sa[r] = 0.0f;
#pragma unroll
            for (int c = 0; c < 4; ++c) {
                bf16x8 kf = *(const bf16x8*)&Kt[(((2 * c + h) << 6) + kh * 32 + q31) * 8];
                sa = __builtin_amdgcn_mfma_f32_32x32x16_bf16(kf, Qf[c], sa, 0, 0, 0);
            }

            // ---- mask + exp2 (fixed-ref softmax). key row = 4h + 8g + e
            const bool diag = (tile == ntiles - 1);
            float p[16];
#pragma unroll
            for (int g = 0; g < 4; ++g) {
                const int mi[4] = {Md[g].x, Md[g].y, Md[g].z, Md[g].w};
#pragma unroll
                for (int e = 0; e < 4; ++e) {
                    const int reg = g * 4 + e;
                    float s = sa[reg];
                    bool keep = (mi[e] != 0);
                    if (diag) {
                        const int keyg = tile * 64 + kh * 32 + 4 * h + 8 * g + e;
                        keep = keep && (keyg <= qrow);
                    }
                    s = keep ? s : -1e30f;
                    p[reg] = fast_exp2(fminf(s, 80.0f));
                    lsum += p[reg];
                }
            }

            // ---- P -> B-fragment via lane^32 exchange
            unsigned u[8], su[8];
#pragma unroll
            for (int i = 0; i < 8; ++i) u[i] = pk2bf(p[2 * i], p[2 * i + 1]);
#pragma unroll
            for (int i = 0; i < 8; ++i) su[i] = (unsigned)__shfl_xor((int)u[i], 32);
            int4 fi0 = h ? (int4){(int)su[2], (int)su[3], (int)u[2], (int)u[3]}
                         : (int4){(int)u[0], (int)u[1], (int)su[0], (int)su[1]};
            int4 fi1 = h ? (int4){(int)su[6], (int)su[7], (int)u[6], (int)u[7]}
                         : (int4){(int)u[4], (int)u[5], (int)su[4], (int)su[5]};
            bf16x8 pf0 = __builtin_bit_cast(bf16x8, fi0);
            bf16x8 pf1 = __builtin_bit_cast(bf16x8, fi1);

            // ---- O^T += V^T @ P^T : D[m=d_local][n=q]
#pragma unroll
            for (int kk = 0; kk < 2; ++kk) {
                const bf16x8 pf = kk ? pf1 : pf0;
#pragma unroll
                for (int nb = 0; nb < 2; ++nb) {
                    bf16x8 vf = *(const bf16x8*)&Vt[(((4 * kh + 2 * kk + h) << 6) + nb * 32 + q31) * 8];
                    Oacc[nb] = __builtin_amdgcn_mfma_f32_32x32x16_bf16(vf, pf, Oacc[nb], 0, 0, 0);
                }
            }
        }
    }

    // ---- epilogue: 4-way merge (kh x tp) per qsub, normalize, store
    lsum += __shfl_xor(lsum, 32);      // both h halves -> per-q l for this wave

    __syncthreads();                    // all K/V LDS reads done -> alias safe
    if (w >= 2) {
        // region r: qsub 0 <- waves {2,4,6} -> r 0,1,2 ; qsub 1 <- {3,5,7} -> 3,4,5
        const int r = ((w - 2) >> 1) + qsub * 3;
        float* Ow = ObF + r * 2048;     // [d 0..63][q 0..31]
#pragma unroll
        for (int nb = 0; nb < 2; ++nb)
#pragma unroll
            for (int g = 0; g < 4; ++g)
#pragma unroll
                for (int e = 0; e < 4; ++e)
                    Ow[(nb * 32 + 4 * h + 8 * g + e) * 32 + q31] = Oacc[nb][g * 4 + e];
        if (h == 0) Lb[w * 32 + q31] = lsum;
    }
    __syncthreads();
    if (w < 2) {
        const int s = w;   // qsub
        const float ltot = lsum + Lb[(s + 2) * 32 + q31] + Lb[(s + 4) * 32 + q31]
                                + Lb[(s + 6) * 32 + q31];
        const float inv = 1.0f / ltot;
        const float* R0 = ObF + (s * 3 + 0) * 2048;
        const float* R1 = ObF + (s * 3 + 1) * 2048;
        const float* R2 = ObF + (s * 3 + 2) * 2048;
        float* op = og + (size_t)b * SEQ * DIM + (size_t)(qbase + s * 32 + q31) * DIM;
#pragma unroll
        for (int nb = 0; nb < 2; ++nb)
#pragma unroll
            for (int g = 0; g < 4; ++g) {
                float4 v4;
                float* vv = (float*)&v4;
#pragma unroll
                for (int e = 0; e < 4; ++e) {
                    const int d = nb * 32 + 4 * h + 8 * g + e;
                    vv[e] = (Oacc[nb][g * 4 + e] + R0[d * 32 + q31] + R1[d * 32 + q31]
                             + R2[d * 32 + q31]) * inv;
                }
                *(float4*)&op[nb * 32 + 4 * h + 8 * g] = v4;
            }
    }
}

extern "C" void kernel_launch(void* const* d_in, const int* in_sizes, int n_in,
                              void* d_out, int out_size, void* d_ws, size_t ws_size,
                              hipStream_t stream) {
    (void)in_sizes; (void)n_in; (void)out_size;
    const float* q = (const float*)d_in[0];
    const float* k = (const float*)d_in[1];
    const float* v = (const float*)d_in[2];
    const int*   m = (const int*)d_in[3];
    float* o = (float*)d_out;
    const size_t need = (size_t)BATCH * NKT * 4096 * sizeof(short) * 2; // 8 MB
    if (ws_size >= need) {
        short* kw = (short*)d_ws;
        short* vw = kw + (size_t)BATCH * NKT * 4096;
        prep_kv<<<dim3(BATCH * NKT), 256, 0, stream>>>(k, v, kw, vw);
        attn_fwd<true><<<dim3(512), 512, 0, stream>>>(q, k, v, m, o, kw, vw);
    } else {
        attn_fwd<false><<<dim3(512), 512, 0, stream>>>(q, k, v, m, o, nullptr, nullptr);
    }
}